// Round 1
// baseline (1140.812 us; speedup 1.0000x reference)
//
#include <hip/hip_runtime.h>
#include <hip/hip_bf16.h>

// Problem constants
#define RES7 7
constexpr int B_ = 64, C_ = 256, H_ = 100, W_ = 152;
constexpr int K_ = C_ * RES7 * RES7;   // 12544
constexpr int R_ = 1024;               // rep
constexpr float SCALE_ = 0.0625f;

constexpr int KSPLIT = 16;
constexpr int KC_PER = K_ / KSPLIT;    // 784
constexpr int KCH = 16;
constexpr int NITER = KC_PER / KCH;    // 49

// ---------------------------------------------------------------------------
// Kernel 1: RoIAlign -> featT4 packed-transposed layout:
//   featT[(k>>2)*256 + b*4 + (k&3)]  == feat[b][k],  k = c*49 + py*7 + px
// One thread per (b, c, py, px).  grid = 64*256*49/256 = 3136 blocks.
// ---------------------------------------------------------------------------
__global__ __launch_bounds__(256) void roi_kernel(const float* __restrict__ x,
                                                  const float* __restrict__ bbox,
                                                  float* __restrict__ featT) {
    int idx = blockIdx.x * 256 + threadIdx.x;
    int b   = idx / K_;
    int rem = idx - b * K_;
    int c   = rem / 49;
    int bin = rem - c * 49;
    int py  = bin / 7;
    int px  = bin - py * 7;

    const float* bb = bbox + b * 4;
    // boxes_xyxy = bbox[:, [0,2,1,3]] -> x1=bb[0], y1=bb[2], x2=bb[1], y2=bb[3]
    float x1 = bb[0] * SCALE_;
    float x2 = bb[1] * SCALE_;
    float y1 = bb[2] * SCALE_;
    float y2 = bb[3] * SCALE_;
    float bin_w = fmaxf(x2 - x1, 1.0f) * (1.0f / RES7);
    float bin_h = fmaxf(y2 - y1, 1.0f) * (1.0f / RES7);

    const float* fplane = x + (size_t)(b * C_ + c) * (H_ * W_);

    float acc = 0.0f;
#pragma unroll
    for (int sy = 0; sy < 2; ++sy) {
        float ysf = y1 + ((float)py + ((float)sy + 0.5f) * 0.5f) * bin_h;
        bool  vy  = (ysf >= -1.0f) && (ysf <= (float)H_);
        float yc  = fminf(fmaxf(ysf, 0.0f), (float)(H_ - 1));
        int   y0  = (int)yc;                    // floor, yc >= 0
        int   y1i = min(y0 + 1, H_ - 1);
        float ly  = yc - (float)y0;
        float hy  = 1.0f - ly;
#pragma unroll
        for (int sx = 0; sx < 2; ++sx) {
            float xsf = x1 + ((float)px + ((float)sx + 0.5f) * 0.5f) * bin_w;
            bool  vx  = (xsf >= -1.0f) && (xsf <= (float)W_);
            float xc  = fminf(fmaxf(xsf, 0.0f), (float)(W_ - 1));
            int   x0  = (int)xc;
            int   x1c = min(x0 + 1, W_ - 1);
            float lx  = xc - (float)x0;
            float hx  = 1.0f - lx;
            if (vy && vx) {
                const float* r0p = fplane + y0  * W_;
                const float* r1p = fplane + y1i * W_;
                float v = hy * (hx * r0p[x0] + lx * r0p[x1c])
                        + ly * (hx * r1p[x0] + lx * r1p[x1c]);
                acc += v;
            }
        }
    }
    int k = c * 49 + bin;
    featT[(k >> 2) * 256 + b * 4 + (k & 3)] = acc * 0.25f;
}

// ---------------------------------------------------------------------------
// Kernel 2: fp32 GEMM  h[b][r] = sum_k feat[b][k] * fc_w[r][k]
// 64x64 output tile per block, split-K=16.  grid = 16 r-tiles * 16 ksplits.
// Writes partials hpart[ks][r][b].
// ---------------------------------------------------------------------------
__global__ __launch_bounds__(256) void gemm_kernel(const float* __restrict__ featT,
                                                   const float* __restrict__ fc_w,
                                                   float* __restrict__ hpart) {
    __shared__ float As[KCH][64];   // [k][b]
    __shared__ float Bs[KCH][64];   // [k][r]

    int t     = threadIdx.x;
    int rt    = blockIdx.x & 15;
    int ks    = blockIdx.x >> 4;
    int r0    = rt * 64;
    int kbase = ks * KC_PER;

    float acc[4][4] = {};           // acc[j(r)][i(b)]
    int b4 = (t & 15) * 4;
    int r4 = (t >> 4) * 4;

    int a_r = t >> 6;               // A-scatter: k_local = a_r*4 + j, b = t&63
    int a_b = t & 63;
    int wr  = t >> 2;               // B-load: local row (0..63)
    int wk  = (t & 3) * 4;          // B-load: k offset (0,4,8,12)

    for (int it = 0; it < NITER; ++it) {
        int k0 = kbase + it * KCH;
        // A chunk: 16 k x 64 b = 1024 contiguous floats in featT4 layout
        float4 av = *reinterpret_cast<const float4*>(featT + k0 * 64 + 4 * t);
        // B chunk: 64 r x 16 k
        float4 bv = *reinterpret_cast<const float4*>(fc_w + (size_t)(r0 + wr) * K_ + k0 + wk);
        __syncthreads();
        As[a_r * 4 + 0][a_b] = av.x;
        As[a_r * 4 + 1][a_b] = av.y;
        As[a_r * 4 + 2][a_b] = av.z;
        As[a_r * 4 + 3][a_b] = av.w;
        Bs[wk + 0][wr] = bv.x;
        Bs[wk + 1][wr] = bv.y;
        Bs[wk + 2][wr] = bv.z;
        Bs[wk + 3][wr] = bv.w;
        __syncthreads();
#pragma unroll
        for (int k = 0; k < KCH; ++k) {
            float4 a  = *reinterpret_cast<const float4*>(&As[k][b4]);
            float4 bb = *reinterpret_cast<const float4*>(&Bs[k][r4]);
            float as[4] = {a.x, a.y, a.z, a.w};
            float bs[4] = {bb.x, bb.y, bb.z, bb.w};
#pragma unroll
            for (int j = 0; j < 4; ++j)
#pragma unroll
                for (int i = 0; i < 4; ++i)
                    acc[j][i] += bs[j] * as[i];
        }
    }

    float* hp = hpart + (size_t)ks * (R_ * 64);
#pragma unroll
    for (int j = 0; j < 4; ++j) {
        float4 v = make_float4(acc[j][0], acc[j][1], acc[j][2], acc[j][3]);
        *reinterpret_cast<float4*>(hp + (r0 + r4 + j) * 64 + b4) = v;
    }
}

// ---------------------------------------------------------------------------
// Kernel 3: reduce split-K partials, bias+ReLU, batch mean/var (wave=64=B),
// normalize, write out[b][r].  One wave per r.  grid = 256 blocks * 4 waves.
// ---------------------------------------------------------------------------
__global__ __launch_bounds__(256) void stats_kernel(const float* __restrict__ hpart,
                                                    const float* __restrict__ fc_b,
                                                    const float* __restrict__ gamma,
                                                    const float* __restrict__ beta,
                                                    float* __restrict__ out) {
    int wv   = threadIdx.x >> 6;
    int lane = threadIdx.x & 63;
    int r    = blockIdx.x * 4 + wv;

    float s = fc_b[r];
#pragma unroll
    for (int ks = 0; ks < KSPLIT; ++ks)
        s += hpart[(size_t)ks * (R_ * 64) + r * 64 + lane];
    float h = fmaxf(s, 0.0f);

    float sum = h, sq = h * h;
#pragma unroll
    for (int off = 32; off >= 1; off >>= 1) {
        sum += __shfl_xor(sum, off);
        sq  += __shfl_xor(sq,  off);
    }
    float mu  = sum * (1.0f / 64.0f);
    float var = sq * (1.0f / 64.0f) - mu * mu;
    out[lane * R_ + r] = (h - mu) * rsqrtf(var + 1e-5f) * gamma[r] + beta[r];
}

extern "C" void kernel_launch(void* const* d_in, const int* in_sizes, int n_in,
                              void* d_out, int out_size, void* d_ws, size_t ws_size,
                              hipStream_t stream) {
    const float* x     = (const float*)d_in[0];
    const float* bbox  = (const float*)d_in[1];
    const float* fc_w  = (const float*)d_in[2];
    const float* fc_b  = (const float*)d_in[3];
    const float* gamma = (const float*)d_in[4];
    const float* beta  = (const float*)d_in[5];
    float* out = (float*)d_out;

    float* featT = (float*)d_ws;                      // K_*64 floats = 3.2 MB
    float* hpart = featT + (size_t)K_ * 64;           // KSPLIT*R_*64 floats = 4 MB

    roi_kernel<<<dim3((B_ * K_) / 256), dim3(256), 0, stream>>>(x, bbox, featT);
    gemm_kernel<<<dim3(16 * KSPLIT), dim3(256), 0, stream>>>(featT, fc_w, hpart);
    stats_kernel<<<dim3(R_ / 4), dim3(256), 0, stream>>>(hpart, fc_b, gamma, beta, out);
}

// Round 2
// 1105.850 us; speedup vs baseline: 1.0316x; 1.0316x over previous
//
#include <hip/hip_runtime.h>
#include <hip/hip_bf16.h>

typedef __attribute__((ext_vector_type(8))) short short8;
typedef __attribute__((ext_vector_type(4))) float f32x4;

// Problem constants
constexpr int B_ = 64, C_ = 256, H_ = 100, W_ = 152;
constexpr int K_ = C_ * 49;            // 12544
constexpr int R_ = 1024;               // rep
constexpr int KB_ = K_ / 32;           // 392 chunks of k=32
constexpr int KG_ = 32;                // split-K groups
constexpr float SCALE_ = 0.0625f;

// fp32 -> bf16 bits, round-to-nearest-even (inputs are finite/normal)
__device__ __forceinline__ short f2bf(float f) {
    unsigned u = __builtin_bit_cast(unsigned, f);
    u += 0x7FFFu + ((u >> 16) & 1u);
    return (short)(u >> 16);
}

// ---------------------------------------------------------------------------
// Kernel 1: RoIAlign -> featT (bf16) in MFMA A-fragment order:
//   featT[(kb*64 + b)*32 + (k & 31)] = feat[b][k],  kb = k>>5, k = c*49+py*7+px
// One thread per (b, c, py, px).  grid = 64*256*49/256 = 3136 blocks.
// ---------------------------------------------------------------------------
__global__ __launch_bounds__(256) void roi_kernel(const float* __restrict__ x,
                                                  const float* __restrict__ bbox,
                                                  short* __restrict__ featT) {
    int idx = blockIdx.x * 256 + threadIdx.x;
    int b   = idx / K_;
    int rem = idx - b * K_;
    int c   = rem / 49;
    int bin = rem - c * 49;
    int py  = bin / 7;
    int px  = bin - py * 7;

    const float* bb = bbox + b * 4;
    // boxes_xyxy = bbox[:, [0,2,1,3]] -> x1=bb[0], y1=bb[2], x2=bb[1], y2=bb[3]
    float x1 = bb[0] * SCALE_;
    float x2 = bb[1] * SCALE_;
    float y1 = bb[2] * SCALE_;
    float y2 = bb[3] * SCALE_;
    float bin_w = fmaxf(x2 - x1, 1.0f) * (1.0f / 7.0f);
    float bin_h = fmaxf(y2 - y1, 1.0f) * (1.0f / 7.0f);

    const float* fplane = x + (size_t)(b * C_ + c) * (H_ * W_);

    float acc = 0.0f;
#pragma unroll
    for (int sy = 0; sy < 2; ++sy) {
        float ysf = y1 + ((float)py + ((float)sy + 0.5f) * 0.5f) * bin_h;
        bool  vy  = (ysf >= -1.0f) && (ysf <= (float)H_);
        float yc  = fminf(fmaxf(ysf, 0.0f), (float)(H_ - 1));
        int   y0  = (int)yc;
        int   y1i = min(y0 + 1, H_ - 1);
        float ly  = yc - (float)y0;
        float hy  = 1.0f - ly;
#pragma unroll
        for (int sx = 0; sx < 2; ++sx) {
            float xsf = x1 + ((float)px + ((float)sx + 0.5f) * 0.5f) * bin_w;
            bool  vx  = (xsf >= -1.0f) && (xsf <= (float)W_);
            float xc  = fminf(fmaxf(xsf, 0.0f), (float)(W_ - 1));
            int   x0  = (int)xc;
            int   x1c = min(x0 + 1, W_ - 1);
            float lx  = xc - (float)x0;
            float hx  = 1.0f - lx;
            if (vy && vx) {
                const float* r0p = fplane + y0  * W_;
                const float* r1p = fplane + y1i * W_;
                acc += hy * (hx * r0p[x0] + lx * r0p[x1c])
                     + ly * (hx * r1p[x0] + lx * r1p[x1c]);
            }
        }
    }
    int k  = c * 49 + bin;
    int kb = k >> 5;
    int kw = k & 31;
    featT[((size_t)kb * 64 + b) * 32 + kw] = f2bf(acc * 0.25f);
}

// ---------------------------------------------------------------------------
// Kernel 2: LDS-free bf16 MFMA GEMM with split-K.
//   h[b][r] = sum_k feat[b][k] * w[r][k]
// grid = (16 r-tiles of 64, KG_ k-groups); block = 256 = 4 waves.
// Wave wv owns 16 rows of w (n-tile).  Per k32 chunk:
//   B-frag: 8 fp32 from fc_w row (r0+lane&15), k = chunk + quad*8.. -> cvt bf16
//   A-frag: 16B from featT (fragment-ordered, perfectly coalesced, L2-hot)
//   4x mfma_f32_16x16x32_bf16 (b-tiles 0..3)
// Writes partials hpart[g][r][b].  No LDS, no barriers.
// ---------------------------------------------------------------------------
__global__ __launch_bounds__(256) void gemm_mfma(const short* __restrict__ featT,
                                                 const float* __restrict__ fc_w,
                                                 float* __restrict__ hpart) {
    int lane = threadIdx.x & 63;
    int wv   = threadIdx.x >> 6;
    int m    = lane & 15;        // n index within tile (r), and b row for A
    int q    = lane >> 4;        // quad: k sub-block
    int r0   = blockIdx.x * 64 + wv * 16;
    int g    = blockIdx.y;

    const float* wrow = fc_w + (size_t)(r0 + m) * K_;

    f32x4 acc0 = {0.f, 0.f, 0.f, 0.f};
    f32x4 acc1 = {0.f, 0.f, 0.f, 0.f};
    f32x4 acc2 = {0.f, 0.f, 0.f, 0.f};
    f32x4 acc3 = {0.f, 0.f, 0.f, 0.f};

    for (int kb = g; kb < KB_; kb += KG_) {
        int k = kb * 32 + q * 8;
        f32x4 w0 = *reinterpret_cast<const f32x4*>(wrow + k);
        f32x4 w1 = *reinterpret_cast<const f32x4*>(wrow + k + 4);
        short8 bfrag;
        bfrag[0] = f2bf(w0[0]); bfrag[1] = f2bf(w0[1]);
        bfrag[2] = f2bf(w0[2]); bfrag[3] = f2bf(w0[3]);
        bfrag[4] = f2bf(w1[0]); bfrag[5] = f2bf(w1[1]);
        bfrag[6] = f2bf(w1[2]); bfrag[7] = f2bf(w1[3]);

        const short* abase = featT + ((size_t)kb * 64 + m) * 32 + q * 8;
        short8 a0 = *reinterpret_cast<const short8*>(abase);
        short8 a1 = *reinterpret_cast<const short8*>(abase + 16 * 32);
        short8 a2 = *reinterpret_cast<const short8*>(abase + 32 * 32);
        short8 a3 = *reinterpret_cast<const short8*>(abase + 48 * 32);

        acc0 = __builtin_amdgcn_mfma_f32_16x16x32_bf16(a0, bfrag, acc0, 0, 0, 0);
        acc1 = __builtin_amdgcn_mfma_f32_16x16x32_bf16(a1, bfrag, acc1, 0, 0, 0);
        acc2 = __builtin_amdgcn_mfma_f32_16x16x32_bf16(a2, bfrag, acc2, 0, 0, 0);
        acc3 = __builtin_amdgcn_mfma_f32_16x16x32_bf16(a3, bfrag, acc3, 0, 0, 0);
    }

    // C/D layout: r = r0 + (lane&15), b = mt*16 + quad*4 + reg
    float* hp = hpart + ((size_t)g * R_ + (r0 + m)) * 64 + q * 4;
#pragma unroll
    for (int i = 0; i < 4; ++i) hp[ 0 + i] = acc0[i];
#pragma unroll
    for (int i = 0; i < 4; ++i) hp[16 + i] = acc1[i];
#pragma unroll
    for (int i = 0; i < 4; ++i) hp[32 + i] = acc2[i];
#pragma unroll
    for (int i = 0; i < 4; ++i) hp[48 + i] = acc3[i];
}

// ---------------------------------------------------------------------------
// Kernel 3: reduce split-K partials, bias+ReLU, batch mean/var (wave=64=B),
// normalize, write out[b][r].  One wave per r.  grid = 256 blocks * 4 waves.
// ---------------------------------------------------------------------------
__global__ __launch_bounds__(256) void stats_kernel(const float* __restrict__ hpart,
                                                    const float* __restrict__ fc_b,
                                                    const float* __restrict__ gamma,
                                                    const float* __restrict__ beta,
                                                    float* __restrict__ out) {
    int wv   = threadIdx.x >> 6;
    int lane = threadIdx.x & 63;
    int r    = blockIdx.x * 4 + wv;

    float s = fc_b[r];
#pragma unroll
    for (int g = 0; g < KG_; ++g)
        s += hpart[((size_t)g * R_ + r) * 64 + lane];
    float h = fmaxf(s, 0.0f);

    float sum = h, sq = h * h;
#pragma unroll
    for (int off = 32; off >= 1; off >>= 1) {
        sum += __shfl_xor(sum, off);
        sq  += __shfl_xor(sq,  off);
    }
    float mu  = sum * (1.0f / 64.0f);
    float var = sq * (1.0f / 64.0f) - mu * mu;
    out[lane * R_ + r] = (h - mu) * rsqrtf(var + 1e-5f) * gamma[r] + beta[r];
}

extern "C" void kernel_launch(void* const* d_in, const int* in_sizes, int n_in,
                              void* d_out, int out_size, void* d_ws, size_t ws_size,
                              hipStream_t stream) {
    const float* x     = (const float*)d_in[0];
    const float* bbox  = (const float*)d_in[1];
    const float* fc_w  = (const float*)d_in[2];
    const float* fc_b  = (const float*)d_in[3];
    const float* gamma = (const float*)d_in[4];
    const float* beta  = (const float*)d_in[5];
    float* out = (float*)d_out;

    short* featT = (short*)d_ws;                               // K_*64 bf16 = 1.6 MB
    float* hpart = (float*)((char*)d_ws + (size_t)K_ * 64 * 2); // KG_*R_*64 f32 = 8 MB

    roi_kernel<<<dim3((B_ * K_) / 256), dim3(256), 0, stream>>>(x, bbox, featT);
    gemm_mfma<<<dim3(16, KG_), dim3(256), 0, stream>>>(featT, fc_w, hpart);
    stats_kernel<<<dim3(R_ / 4), dim3(256), 0, stream>>>(hpart, fc_b, gamma, beta, out);
}